// Round 11
// baseline (2887.145 us; speedup 1.0000x reference)
//
#include <hip/hip_runtime.h>
#include <stdint.h>

#define B_    32
#define T_    512
#define H_    1024
#define H3_   3072
#define EMB_  512

typedef __bf16   bf16x8 __attribute__((ext_vector_type(8)));
typedef float    f32x4  __attribute__((ext_vector_type(4)));
typedef uint32_t u32x4  __attribute__((ext_vector_type(4)));

__device__ __forceinline__ uint32_t f2bf_rne_u(float x){
  union { float f; uint32_t u; } v; v.f = x;
  uint32_t u = v.u;
  return (u + 0x7FFFu + ((u >> 16) & 1u)) >> 16;
}
__device__ __forceinline__ float bf2f(uint32_t h16){
  union { uint32_t u; float f; } v; v.u = h16 << 16; return v.f;
}
__device__ __forceinline__ float sigm(float x){ return 1.f / (1.f + __expf(-x)); }
__device__ __forceinline__ float tanh_f(float x){ float e = __expf(2.f * x); return 1.f - 2.f / (e + 1.f); }

__device__ __forceinline__ f32x4 mfma16(bf16x8 a, bf16x8 b, f32x4 c){
  return __builtin_amdgcn_mfma_f32_16x16x32_bf16(a, b, c, 0, 0, 0);
}

// ---------------- prep kernels ----------------

__global__ void k_emb2bf(const float* __restrict__ src, unsigned short* __restrict__ dst, int n8){
  int i = blockIdx.x * blockDim.x + threadIdx.x;
  if (i >= n8) return;
  const float4* s = (const float4*)src + (size_t)i * 2;
  float4 x = s[0], y = s[1];
  u32x4 o;
  o.x = f2bf_rne_u(x.x) | (f2bf_rne_u(x.y) << 16);
  o.y = f2bf_rne_u(x.z) | (f2bf_rne_u(x.w) << 16);
  o.z = f2bf_rne_u(y.x) | (f2bf_rne_u(y.y) << 16);
  o.w = f2bf_rne_u(y.z) | (f2bf_rne_u(y.w) << 16);
  ((u32x4*)dst)[i] = o;
}

// W (EMB x 3H) -> MFMA B-fragment layout [d][ct(64)][p(3)][ks(16)][lane(64)][8], bf16
__global__ void k_packW(const float* __restrict__ Wf, const float* __restrict__ Wb,
                        unsigned short* __restrict__ out){
  int idx = blockIdx.x * 256 + threadIdx.x;            // 2*64*3*16*64 = 393216
  int lane = idx & 63;
  int ks   = (idx >> 6) & 15;
  int rest = idx >> 10;                                 // d*192 + ct*3 + p
  int p  = rest % 3;
  int ct = (rest / 3) & 63;
  int d  = rest / 192;
  const float* W = d ? Wb : Wf;
  int colg = p * 1024 + ct * 16 + (lane & 15);
  int k0   = ks * 32 + ((lane >> 4) << 3);
  unsigned short* o = out + (size_t)idx * 8;
  #pragma unroll
  for (int b = 0; b < 8; ++b)
    o[b] = (unsigned short)f2bf_rne_u(W[(size_t)(k0 + b) * H3_ + colg]);
}

// U (H x 3H) -> hi/lo split fragment layout [d][ct][p][ks(32)][lane][8]
__global__ void k_packU(const float* __restrict__ Uf, const float* __restrict__ Ub,
                        unsigned short* __restrict__ ohi, unsigned short* __restrict__ olo){
  int idx = blockIdx.x * 256 + threadIdx.x;            // 2*64*3*32*64 = 786432
  int lane = idx & 63;
  int ks   = (idx >> 6) & 31;
  int rest = idx >> 11;                                 // d*192 + ct*3 + p
  int p  = rest % 3;
  int ct = (rest / 3) & 63;
  int d  = rest / 192;
  const float* U = d ? Ub : Uf;
  int colg = p * 1024 + ct * 16 + (lane & 15);
  int k0   = ks * 32 + ((lane >> 4) << 3);
  size_t o = (size_t)idx * 8;
  #pragma unroll
  for (int b = 0; b < 8; ++b){
    float u = U[(size_t)(k0 + b) * H3_ + colg];
    uint32_t hi = f2bf_rne_u(u);
    float lo = u - bf2f(hi);
    ohi[o + b] = (unsigned short)hi;
    olo[o + b] = (unsigned short)f2bf_rne_u(lo);
  }
}

__global__ void k_add(float* __restrict__ out, const float* __restrict__ add, int n4){
  int i = blockIdx.x * blockDim.x + threadIdx.x;
  if (i >= n4) return;
  f32x4 a = __builtin_nontemporal_load((const f32x4*)out + i);
  f32x4 b = __builtin_nontemporal_load((const f32x4*)add + i);
  __builtin_nontemporal_store(a + b, (f32x4*)out + i);
}

// ---------------- persistent GRU kernel ----------------
// grid = 256 blocks x 256 threads = 4 independent chains (dir x row-group).
// chain = 64 blocks; block owns 16 rows x 16 cols; 4 waves split K.
// h exchanged as plain bf16 in MFMA A-fragment order (r8/r9 layout).
// r11 changes:
//  (1) out-stores are NON-TEMPORAL -> the 201MB/dispatch output stream no
//      longer thrashes L3, so the 32MB emb table stays L3-resident (FETCH_SIZE
//      413MB was emb re-misses to HBM caused by that thrash).
//  (2) emb fragments + next-token ride the SAME counted-vmcnt burst as the h
//      slices (4 emb + 8 h + 1 token); xW MFMAs run at vmcnt(9) -> emb RTT and
//      h RTT overlap, and no dependent token->emb load chain precedes the poll.

#define KOUT 8

// one slice: 6 MFMAs (3 gates x {Uhi, Ulo})
#define HP6(E, KS, G0, G1, G2) do { \
  bf16x8 hh_ = __builtin_bit_cast(bf16x8, E); \
  G0 = mfma16(hh_, Uh[0][KS], G0); \
  G0 = mfma16(hh_, Ul[0][KS], G0); \
  G1 = mfma16(hh_, Uh[1][KS], G1); \
  G1 = mfma16(hh_, Ul[1][KS], G1); \
  G2 = mfma16(hh_, Uh[2][KS], G2); \
  G2 = mfma16(hh_, Ul[2][KS], G2); \
} while(0)

__global__ __launch_bounds__(256, 1)
void k_gru(const int* __restrict__ tokens,
           const unsigned char* __restrict__ maskp,
           const unsigned short* __restrict__ embb,
           const unsigned short* __restrict__ WF,
           const unsigned short* __restrict__ UFhi,
           const unsigned short* __restrict__ UFlo,
           const float* __restrict__ bin_f, const float* __restrict__ brec_f,
           const float* __restrict__ bin_b, const float* __restrict__ brec_b,
           unsigned short* __restrict__ hpack, // [4 chain][3 buf][32 ks][64 lane][8] bf16
           uint32_t* flags,                    // [4 chain][4 groups x 32 dwords]
           float* out_f, float* out_b, int atomic_out)
{
  const int blk  = blockIdx.x;
  const int d    = blk >> 7;
  const int rg   = (blk >> 6) & 1;
  const int ct   = blk & 63;
  const int chain = d * 2 + rg;
  const int tid  = threadIdx.x;
  const int lane = tid & 63;
  const int wave = tid >> 6;
  const int l15  = lane & 15;
  const int lg   = lane >> 4;
  const int mask_is32 = (maskp[1] == 0) ? 1 : 0;   // lengths>=128 => mask[0][1]==1 if byte-packed

  const float* bin  = d ? bin_b  : bin_f;
  const float* brec = d ? brec_b : brec_f;
  const int col = ct * 16 + l15;
  const float bz  = bin[col]          + brec[col];
  const float br  = bin[H_ + col]     + brec[H_ + col];
  const float bhx = bin[2 * H_ + col];
  const float bhu = brec[2 * H_ + col];

  // persistent weight fragments in registers
  bf16x8 Uh[3][8], Ul[3][8], Wr[3][4];
  {
    const size_t bu = (size_t)(d * 64 + ct) * (3 * 32 * 64 * 8);
    #pragma unroll
    for (int p = 0; p < 3; ++p)
      #pragma unroll
      for (int ks = 0; ks < 8; ++ks){
        size_t off = bu + ((size_t)(p * 32 + (wave * 8 + ks)) * 64 + lane) * 8;
        Uh[p][ks] = *(const bf16x8*)(UFhi + off);
        Ul[p][ks] = *(const bf16x8*)(UFlo + off);
      }
    const size_t bw = (size_t)(d * 64 + ct) * (3 * 16 * 64 * 8);
    #pragma unroll
    for (int p = 0; p < 3; ++p)
      #pragma unroll
      for (int ks = 0; ks < 4; ++ks){
        size_t off = bw + ((size_t)(p * 16 + (wave * 4 + ks)) * 64 + lane) * 8;
        Wr[p][ks] = *(const bf16x8*)(WF + off);
      }
  }

  __shared__ f32x4 red[2][4][4][64];   // 32 KB: [parity][wave][slot z,r,hx,hu][lane]

  unsigned short* hp16 = hpack + (size_t)chain * 3 * 16384;
  uint32_t* cnt = flags + chain * 128;               // 4 group counters, 128 B apart
  float* outp = atomic_out ? out_f : (d ? out_b : out_f);

  // producer store geometry (fragment order), ushort index for (row r, col c):
  //   (ks0*64 + lgf*16 + r)*8 + jj,  ks0=c>>5, lgf=(c&31)>>3, jj=c&7
  const int ks0 = ct >> 1;
  const int lgf = ((ct & 1) << 1) + (l15 >> 3);
  const int jj  = l15 & 7;
  const int hb_off = ks0 * 512 + lgf * 128 + lg * 32 + jj;   // + i*8 per row

  const f32x4 z4 = {0.f, 0.f, 0.f, 0.f};
  float hreg[4] = {0.f, 0.f, 0.f, 0.f};   // wave 0: own 4 h values (row=lg*4+i)
  float obuf[KOUT][4];                     // wave 0: batched out values

  // token for the CURRENT step, carried in a register (loaded in the previous
  // step's counted burst; initialized here for t=0)
  int tokp = tokens[(rg * 16 + l15) * T_ + (d ? (T_ - 1) : 0)];

  int bcur = 0, bnxt = 1;                  // triple-buffer rotation (t mod 3)

  for (int tb = 0; tb < T_ / KOUT; ++tb){
    #pragma unroll
    for (int ti = 0; ti < KOUT; ++ti){
      const int t   = tb * KOUT + ti;
      const int par = ti & 1;
      const int te  = d ? (T_ - 1 - t) : t;
      const unsigned short* hcur16 = hp16 + (size_t)bcur * 16384;
      unsigned short*       hnxt16 = hp16 + (size_t)bnxt * 16384;

      // mask bytes for the epilogue (L2-resident; drained just below)
      bool mb[4] = {false, false, false, false};
      if (wave == 0){
        #pragma unroll
        for (int i = 0; i < 4; ++i){
          const int row = rg * 16 + (lg << 2) + i;
          const int midx = row * T_ + te;
          mb[i] = mask_is32 ? (((const int*)maskp)[midx] != 0) : (maskp[midx] != 0);
        }
      }

      // drain everything outstanding (mask loads, out-flush nt stores) so the
      // vm counter is exactly 0 when the counted burst issues
      asm volatile("s_waitcnt vmcnt(0)" ::: "memory");
      __builtin_amdgcn_sched_barrier(0);

      // ---- per-wave wait: only THIS wave's 16 producers (group = wave)
      if (t > 0 && lane == 0){
        const uint32_t tgt = (uint32_t)(16 * t);
        while (__hip_atomic_load(cnt + wave * 32, __ATOMIC_RELAXED, __HIP_MEMORY_SCOPE_AGENT) < tgt)
          __builtin_amdgcn_s_sleep(1);
      }

      // ---- counted burst: 4 emb (cacheable) + 8 h slices (sc1) + next token.
      // Queue: [e0..e3, h0..h7, tok] -> waits 9 / 7 / 5 / 3 / 1 / 0.
      const unsigned short* embp = embb + (size_t)tokp * EMB_ + wave * 128 + (lg << 3);
      const unsigned short* a0 = hcur16 + (size_t)wave * 4096 + (size_t)lane * 8;
      const int tn  = (t + 1 < T_) ? (t + 1) : t;
      const int ten = d ? (T_ - 1 - tn) : tn;
      const int* tok_addr = tokens + (rg * 16 + l15) * T_ + ten;
      u32x4 xe[4];
      u32x4 e[8];
      uint32_t toknu;

      asm volatile(
        "global_load_dwordx4 %0, %4, off\n\t"
        "global_load_dwordx4 %1, %4, off offset:64\n\t"
        "global_load_dwordx4 %2, %4, off offset:128\n\t"
        "global_load_dwordx4 %3, %4, off offset:192\n\t"
        : "=&v"(xe[0]), "=&v"(xe[1]), "=&v"(xe[2]), "=&v"(xe[3])
        : "v"(embp));
      asm volatile(
        "global_load_dwordx4 %0, %4, off sc1\n\t"
        "global_load_dwordx4 %1, %4, off offset:1024 sc1\n\t"
        "global_load_dwordx4 %2, %4, off offset:2048 sc1\n\t"
        "global_load_dwordx4 %3, %4, off offset:3072 sc1\n\t"
        : "=&v"(e[0]), "=&v"(e[1]), "=&v"(e[2]), "=&v"(e[3])
        : "v"(a0));
      asm volatile(
        "global_load_dwordx4 %0, %4, off sc1\n\t"
        "global_load_dwordx4 %1, %4, off offset:1024 sc1\n\t"
        "global_load_dwordx4 %2, %4, off offset:2048 sc1\n\t"
        "global_load_dwordx4 %3, %4, off offset:3072 sc1\n\t"
        : "=&v"(e[4]), "=&v"(e[5]), "=&v"(e[6]), "=&v"(e[7])
        : "v"(a0 + 2048));
      asm volatile(
        "global_load_dword %0, %1, off\n\t"
        : "=&v"(toknu) : "v"(tok_addr));

      // ---- xW MFMAs at vmcnt(9): emb ready, h RTT still in flight
      f32x4 ax0 = z4, ax1 = z4, ax2 = z4;
      asm volatile("s_waitcnt vmcnt(9)" ::: "memory");
      __builtin_amdgcn_sched_barrier(0);
      #pragma unroll
      for (int ks = 0; ks < 4; ++ks){
        bf16x8 xa = __builtin_bit_cast(bf16x8, xe[ks]);
        ax0 = mfma16(xa, Wr[0][ks], ax0);
        ax1 = mfma16(xa, Wr[1][ks], ax1);
        ax2 = mfma16(xa, Wr[2][ks], ax2);
      }

      // even/odd accumulator split (6 independent MFMA chains)
      f32x4 zA = z4, zB = z4, rA = z4, rB = z4, uA = z4, uB = z4;

      asm volatile("s_waitcnt vmcnt(7)" ::: "memory");
      __builtin_amdgcn_sched_barrier(0);
      HP6(e[0], 0, zA, rA, uA);
      HP6(e[1], 1, zB, rB, uB);
      asm volatile("s_waitcnt vmcnt(5)" ::: "memory");
      __builtin_amdgcn_sched_barrier(0);
      HP6(e[2], 2, zA, rA, uA);
      HP6(e[3], 3, zB, rB, uB);
      asm volatile("s_waitcnt vmcnt(3)" ::: "memory");
      __builtin_amdgcn_sched_barrier(0);
      HP6(e[4], 4, zA, rA, uA);
      HP6(e[5], 5, zB, rB, uB);
      asm volatile("s_waitcnt vmcnt(1)" ::: "memory");
      __builtin_amdgcn_sched_barrier(0);
      HP6(e[6], 6, zA, rA, uA);
      HP6(e[7], 7, zB, rB, uB);

      // token load done (it was the last queue entry) -- safe to consume
      asm volatile("s_waitcnt vmcnt(0)" ::: "memory");
      __builtin_amdgcn_sched_barrier(0);
      const int tok_next = (int)toknu;

      // ---- cross-wave K-reduction (parity double-buffered)
      red[par][wave][0][lane] = ax0 + zA + zB;
      red[par][wave][1][lane] = ax1 + rA + rB;
      red[par][wave][2][lane] = ax2;
      red[par][wave][3][lane] = uA + uB;
      __syncthreads();

      if (wave == 0){
        f32x4 rz  = red[par][0][0][lane] + red[par][1][0][lane] + red[par][2][0][lane] + red[par][3][0][lane];
        f32x4 rr  = red[par][0][1][lane] + red[par][1][1][lane] + red[par][2][1][lane] + red[par][3][1][lane];
        f32x4 rhx = red[par][0][2][lane] + red[par][1][2][lane] + red[par][2][2][lane] + red[par][3][2][lane];
        f32x4 rhu = red[par][0][3][lane] + red[par][1][3][lane] + red[par][2][3][lane] + red[par][3][3][lane];
        uint32_t hs[4];
        #pragma unroll
        for (int i = 0; i < 4; ++i){
          const float z  = sigm(rz[i] + bz);
          const float r  = sigm(rr[i] + br);
          const float hh = tanh_f(rhx[i] + bhx + r * (rhu[i] + bhu));
          const float hprev = hreg[i];
          const float v = mb[i] ? (z * hprev + (1.f - z) * hh) : hprev;
          hreg[i] = v;
          obuf[ti][i] = v;
          hs[i] = f2bf_rne_u(v);
        }
        unsigned short* hb = hnxt16 + hb_off;   // rows i are +16 B apart
        asm volatile(
          "global_store_short %4, %0, off sc1\n\t"
          "global_store_short %4, %1, off offset:16 sc1\n\t"
          "global_store_short %4, %2, off offset:32 sc1\n\t"
          "global_store_short %4, %3, off offset:48 sc1\n\t"
          :: "v"(hs[0]), "v"(hs[1]), "v"(hs[2]), "v"(hs[3]), "v"(hb)
          : "memory");
        // drain own h stores to the coherence point, then signal arrival
        asm volatile("s_waitcnt vmcnt(0)" ::: "memory");
        if (tid == 0)
          atomicAdd(cnt + (ct >> 4) * 32, 1u);

        // flush batched out values once per KOUT steps with NON-TEMPORAL
        // stores (no L3 allocation -> emb table stays L3-resident); the acks
        // drain at the next iteration's pre-poll vmcnt(0).
        if (ti == KOUT - 1){
          #pragma unroll
          for (int j = 0; j < KOUT; ++j){
            const int tj  = tb * KOUT + j;
            const int tej = d ? (T_ - 1 - tj) : tj;
            #pragma unroll
            for (int i = 0; i < 4; ++i){
              const int row = rg * 16 + (lg << 2) + i;
              const size_t oidx = ((size_t)row * T_ + tej) * H_ + col;
              if (atomic_out) atomicAdd(outp + oidx, obuf[j][i]);
              else            __builtin_nontemporal_store(obuf[j][i], outp + oidx);
            }
          }
        }
      }

      tokp = tok_next;
      const int bt = bnxt + 1;
      bcur = bnxt;
      bnxt = (bt == 3) ? 0 : bt;
    }
  }
}

// ---------------- launch ----------------

extern "C" void kernel_launch(void* const* d_in, const int* in_sizes, int n_in,
                              void* d_out, int out_size, void* d_ws, size_t ws_size,
                              hipStream_t stream) {
  const int*   tokens = (const int*)d_in[0];
  const unsigned char* mask = (const unsigned char*)d_in[1];
  const float* emb   = (const float*)d_in[2];
  const float* Wf    = (const float*)d_in[3];
  const float* Uf    = (const float*)d_in[4];
  const float* bfin  = (const float*)d_in[5];
  const float* bfrec = (const float*)d_in[6];
  const float* Wb    = (const float*)d_in[7];
  const float* Ub    = (const float*)d_in[8];
  const float* bbin  = (const float*)d_in[9];
  const float* bbrec = (const float*)d_in[10];
  float* out = (float*)d_out;
  char*  ws  = (char*)d_ws;

  // workspace layout (bytes)
  const size_t o_embb  = 0;                         // 32000*512*2      = 32,768,000
  const size_t o_wf    = 32768000;                  // 2*64*3*16*64*8*2 =  6,291,456
  const size_t o_ufhi  = 39059456;                  // 2*64*3*32*64*8*2 = 12,582,912
  const size_t o_uflo  = 51642368;                  // 12,582,912
  const size_t o_hpack = 64225280;                  // 4*3*32*64*8*2    =    393,216
  const size_t o_flags = 64618496;                  // 2048
  const size_t o_bwd   = 64620544;                  // 32*512*1024*4    = 67,108,864
  const size_t need_full = o_bwd + 67108864;

  const int atomic_mode = (ws_size < need_full) ? 1 : 0;

  // reset h triple-buffers + counters every call (graph replays don't re-poison)
  hipMemsetAsync(ws + o_hpack, 0, 393216 + 2048, stream);

  k_emb2bf<<<8000, 256, 0, stream>>>(emb, (unsigned short*)(ws + o_embb), 2048000);
  k_packW <<<1536, 256, 0, stream>>>(Wf, Wb, (unsigned short*)(ws + o_wf));
  k_packU <<<3072, 256, 0, stream>>>(Uf, Ub, (unsigned short*)(ws + o_ufhi),
                                             (unsigned short*)(ws + o_uflo));
  if (atomic_mode)
    hipMemsetAsync(out, 0, (size_t)out_size * sizeof(float), stream);

  k_gru<<<256, 256, 0, stream>>>(tokens, mask,
                                 (const unsigned short*)(ws + o_embb),
                                 (const unsigned short*)(ws + o_wf),
                                 (const unsigned short*)(ws + o_ufhi),
                                 (const unsigned short*)(ws + o_uflo),
                                 bfin, bfrec, bbin, bbrec,
                                 (unsigned short*)(ws + o_hpack),
                                 (uint32_t*)(ws + o_flags),
                                 out, (float*)(ws + o_bwd), atomic_mode);

  if (!atomic_mode)
    k_add<<<16384, 256, 0, stream>>>(out, (const float*)(ws + o_bwd), 4194304);
}

// Round 16
// 2729.113 us; speedup vs baseline: 1.0579x; 1.0579x over previous
//
#include <hip/hip_runtime.h>
#include <stdint.h>

#define B_    32
#define T_    512
#define H_    1024
#define H3_   3072
#define EMB_  512

typedef __bf16   bf16x8 __attribute__((ext_vector_type(8)));
typedef float    f32x4  __attribute__((ext_vector_type(4)));
typedef uint32_t u32x4  __attribute__((ext_vector_type(4)));

__device__ __forceinline__ uint32_t f2bf_rne_u(float x){
  union { float f; uint32_t u; } v; v.f = x;
  uint32_t u = v.u;
  return (u + 0x7FFFu + ((u >> 16) & 1u)) >> 16;
}
__device__ __forceinline__ float bf2f(uint32_t h16){
  union { uint32_t u; float f; } v; v.u = h16 << 16; return v.f;
}
__device__ __forceinline__ float sigm(float x){ return 1.f / (1.f + __expf(-x)); }
__device__ __forceinline__ float tanh_f(float x){ float e = __expf(2.f * x); return 1.f - 2.f / (e + 1.f); }

__device__ __forceinline__ f32x4 mfma16(bf16x8 a, bf16x8 b, f32x4 c){
  return __builtin_amdgcn_mfma_f32_16x16x32_bf16(a, b, c, 0, 0, 0);
}

// 2 u32x4 (8 packed words, word = hi16|lo16) -> hi-halves / lo-halves bf16x8
__device__ __forceinline__ bf16x8 upk_hi(u32x4 a, u32x4 b){
  u32x4 r;
  r.x = (a.x >> 16) | (a.y & 0xFFFF0000u);
  r.y = (a.z >> 16) | (a.w & 0xFFFF0000u);
  r.z = (b.x >> 16) | (b.y & 0xFFFF0000u);
  r.w = (b.z >> 16) | (b.w & 0xFFFF0000u);
  return __builtin_bit_cast(bf16x8, r);
}
__device__ __forceinline__ bf16x8 upk_lo(u32x4 a, u32x4 b){
  u32x4 r;
  r.x = (a.x & 0xFFFFu) | (a.y << 16);
  r.y = (a.z & 0xFFFFu) | (a.w << 16);
  r.z = (b.x & 0xFFFFu) | (b.y << 16);
  r.w = (b.z & 0xFFFFu) | (b.w << 16);
  return __builtin_bit_cast(bf16x8, r);
}

// ---------------- prep kernels ----------------

__global__ void k_emb2bf(const float* __restrict__ src, unsigned short* __restrict__ dst, int n8){
  int i = blockIdx.x * blockDim.x + threadIdx.x;
  if (i >= n8) return;
  const float4* s = (const float4*)src + (size_t)i * 2;
  float4 x = s[0], y = s[1];
  u32x4 o;
  o.x = f2bf_rne_u(x.x) | (f2bf_rne_u(x.y) << 16);
  o.y = f2bf_rne_u(x.z) | (f2bf_rne_u(x.w) << 16);
  o.z = f2bf_rne_u(y.x) | (f2bf_rne_u(y.y) << 16);
  o.w = f2bf_rne_u(y.z) | (f2bf_rne_u(y.w) << 16);
  ((u32x4*)dst)[i] = o;
}

// W (EMB x 3H) -> MFMA B-fragment layout [d][ct(64)][p(3)][ks(16)][lane(64)][8], bf16
__global__ void k_packW(const float* __restrict__ Wf, const float* __restrict__ Wb,
                        unsigned short* __restrict__ out){
  int idx = blockIdx.x * 256 + threadIdx.x;            // 2*64*3*16*64 = 393216
  int lane = idx & 63;
  int ks   = (idx >> 6) & 15;
  int rest = idx >> 10;                                 // d*192 + ct*3 + p
  int p  = rest % 3;
  int ct = (rest / 3) & 63;
  int d  = rest / 192;
  const float* W = d ? Wb : Wf;
  int colg = p * 1024 + ct * 16 + (lane & 15);
  int k0   = ks * 32 + ((lane >> 4) << 3);
  unsigned short* o = out + (size_t)idx * 8;
  #pragma unroll
  for (int b = 0; b < 8; ++b)
    o[b] = (unsigned short)f2bf_rne_u(W[(size_t)(k0 + b) * H3_ + colg]);
}

// U (H x 3H) -> hi/lo split fragment layout [d][ct][p][ks(32)][lane][8]
__global__ void k_packU(const float* __restrict__ Uf, const float* __restrict__ Ub,
                        unsigned short* __restrict__ ohi, unsigned short* __restrict__ olo){
  int idx = blockIdx.x * 256 + threadIdx.x;            // 2*64*3*32*64 = 786432
  int lane = idx & 63;
  int ks   = (idx >> 6) & 31;
  int rest = idx >> 11;                                 // d*192 + ct*3 + p
  int p  = rest % 3;
  int ct = (rest / 3) & 63;
  int d  = rest / 192;
  const float* U = d ? Ub : Uf;
  int colg = p * 1024 + ct * 16 + (lane & 15);
  int k0   = ks * 32 + ((lane >> 4) << 3);
  size_t o = (size_t)idx * 8;
  #pragma unroll
  for (int b = 0; b < 8; ++b){
    float u = U[(size_t)(k0 + b) * H3_ + colg];
    uint32_t hi = f2bf_rne_u(u);
    float lo = u - bf2f(hi);
    ohi[o + b] = (unsigned short)hi;
    olo[o + b] = (unsigned short)f2bf_rne_u(lo);
  }
}

__global__ void k_add(float* __restrict__ out, const float* __restrict__ add, int n4){
  int i = blockIdx.x * blockDim.x + threadIdx.x;
  if (i >= n4) return;
  f32x4 a = ((const f32x4*)out)[i];
  f32x4 b = ((const f32x4*)add)[i];
  ((f32x4*)out)[i] = a + b;
}

// ---------------- persistent GRU kernel ----------------
// grid = 256 blocks x 256 threads = 4 independent chains (dir x row-group).
// chain = 64 blocks; block owns 16 rows x 16 cols; 4 waves split K.
// h EXCHANGED IN MFMA-FRAGMENT ORDER: hpack[chain][buf][ks(32)][lane(64)][8w]
// (word = hi16|lo16 of h[row=lane&15][k=ks*32+(lane>>4)*8+j]). Producer
// scatters its 16x16 tile into fragment order (stores off critical path);
// consumer wave w reads its 8 slices as CONTIGUOUS 2 KB wave-wide loads.
// sc1 loads (L3-coherent), no cache fences (r7 regression), no XCD-local
// games (r13/r14/r15 regressions). r16 change: polls BUSY-SPIN (no s_sleep)
// -- s_sleep advertises idleness to the power manager; if DVFS was clocking
// this mostly-sleeping kernel down, every RTT on the serial chain pays it.

#define KOUT 8

#define HPROC(PA, PB, KS, G0, G1, G2) do { \
  bf16x8 hh_ = upk_hi(PA, PB); \
  bf16x8 hl_ = upk_lo(PA, PB); \
  G0 = mfma16(hh_, Uh[0][KS], G0); \
  G0 = mfma16(hl_, Uh[0][KS], G0); \
  G0 = mfma16(hh_, Ul[0][KS], G0); \
  G1 = mfma16(hh_, Uh[1][KS], G1); \
  G1 = mfma16(hl_, Uh[1][KS], G1); \
  G1 = mfma16(hh_, Ul[1][KS], G1); \
  G2 = mfma16(hh_, Uh[2][KS], G2); \
  G2 = mfma16(hl_, Uh[2][KS], G2); \
  G2 = mfma16(hh_, Ul[2][KS], G2); \
} while(0)

__global__ __launch_bounds__(256, 1)
void k_gru(const int* __restrict__ tokens,
           const unsigned char* __restrict__ maskp,
           const unsigned short* __restrict__ embb,
           const unsigned short* __restrict__ WF,
           const unsigned short* __restrict__ UFhi,
           const unsigned short* __restrict__ UFlo,
           const float* __restrict__ bin_f, const float* __restrict__ brec_f,
           const float* __restrict__ bin_b, const float* __restrict__ brec_b,
           uint32_t* __restrict__ hpack,   // [4 chain][3 buf][32 ks][64 lane][8] u32
           uint32_t* flags,                // [4 chain][4 groups x 32 dwords]
           float* out_f, float* out_b, int atomic_out)
{
  const int blk  = blockIdx.x;
  const int d    = blk >> 7;
  const int rg   = (blk >> 6) & 1;
  const int ct   = blk & 63;
  const int chain = d * 2 + rg;
  const int tid  = threadIdx.x;
  const int lane = tid & 63;
  const int wave = tid >> 6;
  const int l15  = lane & 15;
  const int lg   = lane >> 4;
  const int mask_is32 = (maskp[1] == 0) ? 1 : 0;   // lengths>=128 => mask[0][1]==1 if byte-packed

  const float* bin  = d ? bin_b  : bin_f;
  const float* brec = d ? brec_b : brec_f;
  const int col = ct * 16 + l15;
  const float bz  = bin[col]          + brec[col];
  const float br  = bin[H_ + col]     + brec[H_ + col];
  const float bhx = bin[2 * H_ + col];
  const float bhu = brec[2 * H_ + col];

  // persistent weight fragments in registers
  bf16x8 Uh[3][8], Ul[3][8], Wr[3][4];
  {
    const size_t bu = (size_t)(d * 64 + ct) * (3 * 32 * 64 * 8);
    #pragma unroll
    for (int p = 0; p < 3; ++p)
      #pragma unroll
      for (int ks = 0; ks < 8; ++ks){
        size_t off = bu + ((size_t)(p * 32 + (wave * 8 + ks)) * 64 + lane) * 8;
        Uh[p][ks] = *(const bf16x8*)(UFhi + off);
        Ul[p][ks] = *(const bf16x8*)(UFlo + off);
      }
    const size_t bw = (size_t)(d * 64 + ct) * (3 * 16 * 64 * 8);
    #pragma unroll
    for (int p = 0; p < 3; ++p)
      #pragma unroll
      for (int ks = 0; ks < 4; ++ks){
        size_t off = bw + ((size_t)(p * 16 + (wave * 4 + ks)) * 64 + lane) * 8;
        Wr[p][ks] = *(const bf16x8*)(WF + off);
      }
  }

  __shared__ f32x4 red[2][4][4][64];   // 32 KB: [parity][wave][slot z,r,hx,hu][lane]

  uint32_t* hp  = hpack + (size_t)chain * 3 * 16 * H_;
  uint32_t* cnt = flags + chain * 128;               // 4 group counters, 128 B apart
  float* outp = atomic_out ? out_f : (d ? out_b : out_f);

  // producer store geometry (fragment order): word index for (row r, col c):
  //   (ks0*64 + lgf*16 + r)*8 + jj,  ks0=c>>5, lgf=(c&31)>>3, jj=c&7
  const int ks0 = ct >> 1;
  const int lgf = ((ct & 1) << 1) + (l15 >> 3);
  const int jj  = l15 & 7;
  const int hb_off = ks0 * 512 + lgf * 128 + lg * 32 + jj;   // + i*8 per row

  const f32x4 z4 = {0.f, 0.f, 0.f, 0.f};
  float hreg[4] = {0.f, 0.f, 0.f, 0.f};   // wave 0: own 4 h values (row=lg*4+i)
  float obuf[KOUT][4];                     // wave 0: batched out values

  int bcur = 0, bnxt = 1;                  // triple-buffer rotation (t mod 3)

  for (int tb = 0; tb < T_ / KOUT; ++tb){
    #pragma unroll
    for (int ti = 0; ti < KOUT; ++ti){
      const int t   = tb * KOUT + ti;
      const int par = ti & 1;
      const int te  = d ? (T_ - 1 - t) : t;
      const uint32_t* hcur = hp + (size_t)bcur * 16 * H_;
      uint32_t*       hnxt = hp + (size_t)bnxt * 16 * H_;

      // mask prefetch (wave 0 epilogue rows)
      bool mb[4] = {false, false, false, false};
      if (wave == 0){
        #pragma unroll
        for (int i = 0; i < 4; ++i){
          const int row = rg * 16 + (lg << 2) + i;
          const int midx = row * T_ + te;
          mb[i] = mask_is32 ? (((const int*)maskp)[midx] != 0) : (maskp[midx] != 0);
        }
      }

      // ---- input projection x@W (h-independent; overlaps the wait)
      f32x4 ax0 = z4, ax1 = z4, ax2 = z4;
      const int tok0 = tokens[(rg * 16 + l15) * T_ + te];
      #pragma unroll
      for (int ks = 0; ks < 4; ++ks){
        const int koff = (wave * 4 + ks) * 32 + (lg << 3);
        bf16x8 xa0 = *(const bf16x8*)(embb + (size_t)tok0 * EMB_ + koff);
        ax0 = mfma16(xa0, Wr[0][ks], ax0);
        ax1 = mfma16(xa0, Wr[1][ks], ax1);
        ax2 = mfma16(xa0, Wr[2][ks], ax2);
      }

      // drain everything outstanding (mask/emb loads, out-flush stores) while
      // we still have wait slack -> vm counter exact for the burst
      asm volatile("s_waitcnt vmcnt(0)" ::: "memory");
      __builtin_amdgcn_sched_barrier(0);

      // ---- per-wave wait: only THIS wave's 16 producers (group = wave)
      // BUSY-SPIN: no s_sleep -- keep the CU visibly active so DVFS doesn't
      // downclock the serial chain; the L3 load RTT itself paces the loop.
      if (t > 0 && lane == 0){
        const uint32_t tgt = (uint32_t)(16 * t);
        while (__hip_atomic_load(cnt + wave * 32, __ATOMIC_RELAXED, __HIP_MEMORY_SCOPE_AGENT) < tgt)
          ;
      }

      // ---- recurrent path: wave reads its 8 slices CONTIGUOUSLY.
      // slice s: lane reads 32B at ((wave*8+s)*64 + lane)*32 bytes.
      const uint32_t* a0 = hcur + (size_t)wave * 4096 + (size_t)lane * 8;
      u32x4 e[16];

      asm volatile(
        "global_load_dwordx4 %0, %4, off sc1\n\t"
        "global_load_dwordx4 %1, %4, off offset:16 sc1\n\t"
        "global_load_dwordx4 %2, %4, off offset:2048 sc1\n\t"
        "global_load_dwordx4 %3, %4, off offset:2064 sc1\n\t"
        : "=&v"(e[0]), "=&v"(e[1]), "=&v"(e[2]), "=&v"(e[3])
        : "v"(a0));
      asm volatile(
        "global_load_dwordx4 %0, %4, off sc1\n\t"
        "global_load_dwordx4 %1, %4, off offset:16 sc1\n\t"
        "global_load_dwordx4 %2, %4, off offset:2048 sc1\n\t"
        "global_load_dwordx4 %3, %4, off offset:2064 sc1\n\t"
        : "=&v"(e[4]), "=&v"(e[5]), "=&v"(e[6]), "=&v"(e[7])
        : "v"(a0 + 1024));
      asm volatile(
        "global_load_dwordx4 %0, %4, off sc1\n\t"
        "global_load_dwordx4 %1, %4, off offset:16 sc1\n\t"
        "global_load_dwordx4 %2, %4, off offset:2048 sc1\n\t"
        "global_load_dwordx4 %3, %4, off offset:2064 sc1\n\t"
        : "=&v"(e[8]), "=&v"(e[9]), "=&v"(e[10]), "=&v"(e[11])
        : "v"(a0 + 2048));
      asm volatile(
        "global_load_dwordx4 %0, %4, off sc1\n\t"
        "global_load_dwordx4 %1, %4, off offset:16 sc1\n\t"
        "global_load_dwordx4 %2, %4, off offset:2048 sc1\n\t"
        "global_load_dwordx4 %3, %4, off offset:2064 sc1\n\t"
        : "=&v"(e[12]), "=&v"(e[13]), "=&v"(e[14]), "=&v"(e[15])
        : "v"(a0 + 3072));

      // even/odd accumulator split (6 independent MFMA chains)
      f32x4 zA = z4, zB = z4, rA = z4, rB = z4, uA = z4, uB = z4;

      asm volatile("s_waitcnt vmcnt(12)" ::: "memory");
      __builtin_amdgcn_sched_barrier(0);
      HPROC(e[0],  e[1],  0, zA, rA, uA);
      HPROC(e[2],  e[3],  1, zB, rB, uB);
      asm volatile("s_waitcnt vmcnt(8)" ::: "memory");
      __builtin_amdgcn_sched_barrier(0);
      HPROC(e[4],  e[5],  2, zA, rA, uA);
      HPROC(e[6],  e[7],  3, zB, rB, uB);
      asm volatile("s_waitcnt vmcnt(4)" ::: "memory");
      __builtin_amdgcn_sched_barrier(0);
      HPROC(e[8],  e[9],  4, zA, rA, uA);
      HPROC(e[10], e[11], 5, zB, rB, uB);
      asm volatile("s_waitcnt vmcnt(0)" ::: "memory");
      __builtin_amdgcn_sched_barrier(0);
      HPROC(e[12], e[13], 6, zA, rA, uA);
      HPROC(e[14], e[15], 7, zB, rB, uB);

      // ---- cross-wave K-reduction (parity double-buffered)
      red[par][wave][0][lane] = ax0 + zA + zB;
      red[par][wave][1][lane] = ax1 + rA + rB;
      red[par][wave][2][lane] = ax2;
      red[par][wave][3][lane] = uA + uB;
      __syncthreads();

      if (wave == 0){
        f32x4 rz  = red[par][0][0][lane] + red[par][1][0][lane] + red[par][2][0][lane] + red[par][3][0][lane];
        f32x4 rr  = red[par][0][1][lane] + red[par][1][1][lane] + red[par][2][1][lane] + red[par][3][1][lane];
        f32x4 rhx = red[par][0][2][lane] + red[par][1][2][lane] + red[par][2][2][lane] + red[par][3][2][lane];
        f32x4 rhu = red[par][0][3][lane] + red[par][1][3][lane] + red[par][2][3][lane] + red[par][3][3][lane];
        uint32_t* hb = hnxt + hb_off;
        #pragma unroll
        for (int i = 0; i < 4; ++i){
          const float z  = sigm(rz[i] + bz);
          const float r  = sigm(rr[i] + br);
          const float hh = tanh_f(rhx[i] + bhx + r * (rhu[i] + bhu));
          const float hprev = hreg[i];
          const float v = mb[i] ? (z * hprev + (1.f - z) * hh) : hprev;
          hreg[i] = v;
          obuf[ti][i] = v;
          const uint32_t hi = f2bf_rne_u(v);
          const float lo = v - bf2f(hi);
          __hip_atomic_store(hb + i * 8, (hi << 16) | f2bf_rne_u(lo),
                             __ATOMIC_RELAXED, __HIP_MEMORY_SCOPE_AGENT);
        }
        // drain own h stores to the coherence point, then signal arrival
        asm volatile("s_waitcnt vmcnt(0)" ::: "memory");
        if (tid == 0)
          atomicAdd(cnt + (ct >> 4) * 32, 1u);

        // flush batched out values once per KOUT steps (drains at next
        // iteration's pre-poll vmcnt(0), inside the wait slack)
        if (ti == KOUT - 1){
          #pragma unroll
          for (int j = 0; j < KOUT; ++j){
            const int tj  = tb * KOUT + j;
            const int tej = d ? (T_ - 1 - tj) : tj;
            #pragma unroll
            for (int i = 0; i < 4; ++i){
              const int row = rg * 16 + (lg << 2) + i;
              const size_t oidx = ((size_t)row * T_ + tej) * H_ + col;
              if (atomic_out) atomicAdd(outp + oidx, obuf[j][i]);
              else            outp[oidx] = obuf[j][i];
            }
          }
        }
      }

      const int bt = bnxt + 1;
      bcur = bnxt;
      bnxt = (bt == 3) ? 0 : bt;
    }
  }
}

// ---------------- launch ----------------

extern "C" void kernel_launch(void* const* d_in, const int* in_sizes, int n_in,
                              void* d_out, int out_size, void* d_ws, size_t ws_size,
                              hipStream_t stream) {
  const int*   tokens = (const int*)d_in[0];
  const unsigned char* mask = (const unsigned char*)d_in[1];
  const float* emb   = (const float*)d_in[2];
  const float* Wf    = (const float*)d_in[3];
  const float* Uf    = (const float*)d_in[4];
  const float* bfin  = (const float*)d_in[5];
  const float* bfrec = (const float*)d_in[6];
  const float* Wb    = (const float*)d_in[7];
  const float* Ub    = (const float*)d_in[8];
  const float* bbin  = (const float*)d_in[9];
  const float* bbrec = (const float*)d_in[10];
  float* out = (float*)d_out;
  char*  ws  = (char*)d_ws;

  // workspace layout (bytes)
  const size_t o_embb  = 0;                         // 32000*512*2      = 32,768,000
  const size_t o_wf    = 32768000;                  // 2*64*3*16*64*8*2 =  6,291,456
  const size_t o_ufhi  = 39059456;                  // 2*64*3*32*64*8*2 = 12,582,912
  const size_t o_uflo  = 51642368;                  // 12,582,912
  const size_t o_hpack = 64225280;                  // 4*3*32*64*8*4    =    786,432
  const size_t o_flags = 65011712;                  // 2048
  const size_t o_bwd   = 65013760;                  // 32*512*1024*4    = 67,108,864
  const size_t need_full = o_bwd + 67108864;

  const int atomic_mode = (ws_size < need_full) ? 1 : 0;

  // reset h triple-buffers + counters every call (graph replays don't re-poison)
  hipMemsetAsync(ws + o_hpack, 0, 786432 + 2048, stream);

  k_emb2bf<<<8000, 256, 0, stream>>>(emb, (unsigned short*)(ws + o_embb), 2048000);
  k_packW <<<1536, 256, 0, stream>>>(Wf, Wb, (unsigned short*)(ws + o_wf));
  k_packU <<<3072, 256, 0, stream>>>(Uf, Ub, (unsigned short*)(ws + o_ufhi),
                                             (unsigned short*)(ws + o_uflo));
  if (atomic_mode)
    hipMemsetAsync(out, 0, (size_t)out_size * sizeof(float), stream);

  k_gru<<<256, 256, 0, stream>>>(tokens, mask,
                                 (const unsigned short*)(ws + o_embb),
                                 (const unsigned short*)(ws + o_wf),
                                 (const unsigned short*)(ws + o_ufhi),
                                 (const unsigned short*)(ws + o_uflo),
                                 bfin, bfrec, bbin, bbrec,
                                 (uint32_t*)(ws + o_hpack),
                                 (uint32_t*)(ws + o_flags),
                                 out, (float*)(ws + o_bwd), atomic_mode);

  if (!atomic_mode)
    k_add<<<16384, 256, 0, stream>>>(out, (const float*)(ws + o_bwd), 4194304);
}